// Round 11
// baseline (94.866 us; speedup 1.0000x reference)
//
#include <hip/hip_runtime.h>
#include <cmath>

// BKT forward, B independent students, serial T-step fp32 recurrence.
//
// NUMERICS (R1-R3): harness validates vs fp32 numpy recompute; recurrence
// amplifies rounding ~2e5x over 512 steps -> must replicate np's fp32 op
// order exactly (no FMA contraction, separate rounded mul/add/div, fp64
// sigmoid rounded once). Passing absmax = 0.0039. DO NOT reassociate.
//
// PERF history:
//  R3: scattered stores, 268us -> R4 reg-buffer 153 -> R5 launch_bounds 122
//  R6: LDS-transpose 128B-line stores -> 90us
//  R7: 256B chunks -> null. R8: fine interleave -> 96 (regressed).
//  R9/R10: phase-separated pure-read then pure-write + nontemporal -> 82.7us.
//  R11 (this): writes still ran ~4.6 TB/s vs memset 7.0 -> hypothesis: it's
//      STREAM CONTIGUITY (memset = wave-contiguous; ours = 128B @ 2048B
//      stride). Two-pass: pass1 (thread/student) reads y, packs bits, and
//      records the chain's latent SEED at each 32-step boundary -> ws
//      (9.4 MB). pass2 (16 threads/student, 4+ waves/SIMD TLP) replays each
//      chunk from its seed (bit-identical) and stores via LDS full-row
//      transpose: 8KB FULLY CONTIGUOUS per wave = memset shape.

typedef float floatx4 __attribute__((ext_vector_type(4)));

// ---------------- pass 1: chain + seed/bit extraction ----------------
__global__ __launch_bounds__(256, 1) void bkt_seed(
    const int* __restrict__ X, const int* __restrict__ Y,
    const float* __restrict__ learn_w, const float* __restrict__ guess_w,
    const float* __restrict__ slip_w,  const float* __restrict__ prior_w,
    float* __restrict__ seeds,        // (B,16) latent at chunk starts
    unsigned int* __restrict__ bits,  // (B,16) packed y, 32 steps/word
    float* __restrict__ prm,          // (B,4) l,g,s,p
    int B, int T)
{
#pragma clang fp contract(off)
    const int b = blockIdx.x * 256 + threadIdx.x;

    const int4 xi = *reinterpret_cast<const int4*>(X + (size_t)b * 4);
    const float l = (float)(1.0 / (1.0 + exp(-(double)learn_w[xi.x])));
    const float g = (float)(1.0 / (1.0 + exp(-(double)guess_w[xi.y])));
    const float s = (float)(1.0 / (1.0 + exp(-(double)slip_w[xi.z])));
    const float p = (float)(1.0 / (1.0 + exp(-(double)prior_w[xi.w])));

    const float oms = 1.0f - s, omg = 1.0f - g;
    const float lo = 1e-6f, hi = (float)(1.0 - 1e-6);
    float latent = p;

    const int4* __restrict__ yv = reinterpret_cast<const int4*>(Y + (size_t)b * T);

    int4 cur[8], nxt[8];
    #pragma unroll
    for (int q = 0; q < 8; ++q) cur[q] = yv[q];

    float sd[16];
    unsigned int yw[16];

    for (int o = 0; o < 16; ++o) {
        if (o + 1 < 16) {                      // prefetch next word's y
            #pragma unroll
            for (int q = 0; q < 8; ++q) nxt[q] = yv[(o + 1) * 8 + q];
        }
        unsigned int m = 0;                    // pack current word
        #pragma unroll
        for (int q = 0; q < 8; ++q) {
            m |= (cur[q].x > 0 ? 1u : 0u) << (q * 4 + 0);
            m |= (cur[q].y > 0 ? 1u : 0u) << (q * 4 + 1);
            m |= (cur[q].z > 0 ? 1u : 0u) << (q * 4 + 2);
            m |= (cur[q].w > 0 ? 1u : 0u) << (q * 4 + 3);
        }
        yw[o] = m;
        sd[o] = latent;                        // seed = latent at chunk start

        #pragma unroll
        for (int j = 0; j < 32; ++j) {         // EXACT np fp32 op order
            const float a       = latent * oms;
            const float omlat   = 1.0f - latent;
            const float t1      = omlat * g;
            const float correct = a + t1;
            const float n0      = latent * s;
            const float t2      = omlat * omg;
            const float d0      = n0 + t2;
            const bool hit = (m >> j) & 1u;
            const float num = hit ? a : n0;
            const float den = hit ? correct : d0;
            const float k   = num / den;
            (void)correct;
            const float omk = 1.0f - k;
            const float t3  = omk * l;
            const float nxt2 = k + t3;
            latent = fminf(fmaxf(nxt2, lo), hi);
        }
        #pragma unroll
        for (int q = 0; q < 8; ++q) cur[q] = nxt[q];
    }

    #pragma unroll
    for (int q = 0; q < 4; ++q)
        *reinterpret_cast<float4*>(seeds + (size_t)b * 16 + q * 4) =
            make_float4(sd[4*q], sd[4*q+1], sd[4*q+2], sd[4*q+3]);
    #pragma unroll
    for (int q = 0; q < 4; ++q)
        *reinterpret_cast<uint4*>(bits + (size_t)b * 16 + q * 4) =
            make_uint4(yw[4*q], yw[4*q+1], yw[4*q+2], yw[4*q+3]);
    *reinterpret_cast<float4*>(prm + (size_t)b * 4) = make_float4(l, g, s, p);
}

// ---------------- pass 2: chunk replay + contiguous writer ----------------
__global__ __launch_bounds__(256) void bkt_emit(
    const float* __restrict__ seeds, const unsigned int* __restrict__ bits,
    const float* __restrict__ prm, float* __restrict__ out, int B, int T)
{
#pragma clang fp contract(off)
    const int tid = threadIdx.x;
    const int stl = tid >> 4;                  // student-local 0..15
    const int ch  = tid & 15;                  // chunk 0..15
    const size_t st = (size_t)blockIdx.x * 16 + stl;

    const float4 pr = *reinterpret_cast<const float4*>(prm + st * 4);
    const float l = pr.x, g = pr.y, s = pr.z;
    const float oms = 1.0f - s, omg = 1.0f - g;
    const float lo = 1e-6f, hi = (float)(1.0 - 1e-6);

    float latent = seeds[st * 16 + ch];
    const unsigned int m = bits[st * 16 + ch];

    float cr[32], lt[32];
    #pragma unroll
    for (int j = 0; j < 32; ++j) {             // EXACT np fp32 op order
        const float a       = latent * oms;
        const float omlat   = 1.0f - latent;
        const float t1      = omlat * g;
        const float correct = a + t1;
        const float n0      = latent * s;
        const float t2      = omlat * omg;
        const float d0      = n0 + t2;
        const bool hit = (m >> j) & 1u;
        const float num = hit ? a : n0;
        const float den = hit ? correct : d0;
        const float k   = num / den;
        cr[j] = correct;
        lt[j] = latent;
        const float omk = 1.0f - k;
        const float t3  = omk * l;
        const float nxt = k + t3;
        latent = fminf(fmaxf(nxt, lo), hi);
    }

    __shared__ float xs[16 * 512];             // 32 KB: 16 students x full row

    const int wv = tid >> 6, ln = tid & 63;
    float* __restrict__ myseg = xs + stl * 512 + ch * 32;  // my 128B segment

    // cr: swizzled LDS write, permuted dense read, 8KB-contiguous stores
    #pragma unroll
    for (int q = 0; q < 8; ++q)
        *reinterpret_cast<float4*>(myseg + ((q ^ (ch & 7)) << 2)) =
            make_float4(cr[4*q], cr[4*q+1], cr[4*q+2], cr[4*q+3]);
    __syncthreads();
    #pragma unroll
    for (int i = 0; i < 8; ++i) {
        const int srow = wv * 4 + (i >> 1);    // student-local row
        const int f4   = (i & 1) * 64 + ln;    // logical float4 idx in row
        const int chx  = f4 >> 3, qx = f4 & 7;
        const floatx4 v = *reinterpret_cast<const floatx4*>(
            xs + srow * 512 + chx * 32 + ((qx ^ (chx & 7)) << 2));
        const size_t row = (size_t)blockIdx.x * 16 + srow;
        __builtin_nontemporal_store(v,
            reinterpret_cast<floatx4*>(out + row * T + f4 * 4));
    }
    __syncthreads();

    // lt
    #pragma unroll
    for (int q = 0; q < 8; ++q)
        *reinterpret_cast<float4*>(myseg + ((q ^ (ch & 7)) << 2)) =
            make_float4(lt[4*q], lt[4*q+1], lt[4*q+2], lt[4*q+3]);
    __syncthreads();
    #pragma unroll
    for (int i = 0; i < 8; ++i) {
        const int srow = wv * 4 + (i >> 1);
        const int f4   = (i & 1) * 64 + ln;
        const int chx  = f4 >> 3, qx = f4 & 7;
        const floatx4 v = *reinterpret_cast<const floatx4*>(
            xs + srow * 512 + chx * 32 + ((qx ^ (chx & 7)) << 2));
        const size_t row = (size_t)blockIdx.x * 16 + srow;
        __builtin_nontemporal_store(v,
            reinterpret_cast<floatx4*>(out + (size_t)B * T + row * T + f4 * 4));
    }
}

// ---------------- fallback: R10 single-kernel (ws too small) ----------------
#define LSTR 36
__global__ __launch_bounds__(256, 1) void bkt_fwd(
    const int* __restrict__ X, const int* __restrict__ Y,
    const float* __restrict__ learn_w, const float* __restrict__ guess_w,
    const float* __restrict__ slip_w,  const float* __restrict__ prior_w,
    float* __restrict__ out, int B, int T)
{
#pragma clang fp contract(off)
    const int tid = threadIdx.x;
    const int b = blockIdx.x * 256 + tid;
    __shared__ float xp[256 * LSTR];

    const int4 xi = *reinterpret_cast<const int4*>(X + (size_t)b * 4);
    const float l = (float)(1.0 / (1.0 + exp(-(double)learn_w[xi.x])));
    const float g = (float)(1.0 / (1.0 + exp(-(double)guess_w[xi.y])));
    const float s = (float)(1.0 / (1.0 + exp(-(double)slip_w[xi.z])));
    const float p = (float)(1.0 / (1.0 + exp(-(double)prior_w[xi.w])));
    const float oms = 1.0f - s, omg = 1.0f - g;
    const float lo = 1e-6f, hi = (float)(1.0 - 1e-6);
    float latent = p;

    const int4* __restrict__ yv = reinterpret_cast<const int4*>(Y + (size_t)b * T);
    unsigned int yp[16];
    #pragma unroll
    for (int w = 0; w < 16; ++w) {
        unsigned int mm = 0;
        #pragma unroll
        for (int q = 0; q < 8; ++q) {
            const int4 v = yv[w * 8 + q];
            mm |= (v.x > 0 ? 1u : 0u) << (q * 4 + 0);
            mm |= (v.y > 0 ? 1u : 0u) << (q * 4 + 1);
            mm |= (v.z > 0 ? 1u : 0u) << (q * 4 + 2);
            mm |= (v.w > 0 ? 1u : 0u) << (q * 4 + 3);
        }
        yp[w] = mm;
    }
    const int wv = tid >> 6, ln = tid & 63;
    const int r8 = ln >> 3, c8 = ln & 7;
    float* __restrict__ lrow = xp + tid * LSTR;
    const float* __restrict__ lrd = xp + (wv * 64 + r8) * LSTR + c8 * 4;
    float* __restrict__ gco = out + (size_t)(blockIdx.x * 256 + wv * 64 + r8) * T + c8 * 4;
    float* __restrict__ gla = gco + (size_t)B * T;

    for (int o = 0; o < 16; ++o) {
        const unsigned int ycur = yp[0];
        float cr[32], lt[32];
        #pragma unroll
        for (int j = 0; j < 32; ++j) {
            const float a       = latent * oms;
            const float omlat   = 1.0f - latent;
            const float t1      = omlat * g;
            const float correct = a + t1;
            const float n0      = latent * s;
            const float t2      = omlat * omg;
            const float d0      = n0 + t2;
            const bool hit = (ycur >> j) & 1u;
            const float num = hit ? a : n0;
            const float den = hit ? correct : d0;
            const float k   = num / den;
            cr[j] = correct; lt[j] = latent;
            const float omk = 1.0f - k;
            const float t3  = omk * l;
            const float nxt = k + t3;
            latent = fminf(fmaxf(nxt, lo), hi);
        }
        const int colo = o * 32;
        #pragma unroll
        for (int q = 0; q < 8; ++q)
            *reinterpret_cast<float4*>(lrow + q * 4) =
                make_float4(cr[4*q], cr[4*q+1], cr[4*q+2], cr[4*q+3]);
        __builtin_amdgcn_wave_barrier();
        #pragma unroll
        for (int q = 0; q < 8; ++q) {
            const floatx4 v = *reinterpret_cast<const floatx4*>(lrd + (q * 8) * LSTR);
            __builtin_nontemporal_store(v,
                reinterpret_cast<floatx4*>(gco + (size_t)(q * 8) * T + colo));
        }
        __builtin_amdgcn_wave_barrier();
        #pragma unroll
        for (int q = 0; q < 8; ++q)
            *reinterpret_cast<float4*>(lrow + q * 4) =
                make_float4(lt[4*q], lt[4*q+1], lt[4*q+2], lt[4*q+3]);
        __builtin_amdgcn_wave_barrier();
        #pragma unroll
        for (int q = 0; q < 8; ++q) {
            const floatx4 v = *reinterpret_cast<const floatx4*>(lrd + (q * 8) * LSTR);
            __builtin_nontemporal_store(v,
                reinterpret_cast<floatx4*>(gla + (size_t)(q * 8) * T + colo));
        }
        __builtin_amdgcn_wave_barrier();
        #pragma unroll
        for (int w = 0; w < 15; ++w) yp[w] = yp[w + 1];
    }
}

extern "C" void kernel_launch(void* const* d_in, const int* in_sizes, int n_in,
                              void* d_out, int out_size, void* d_ws, size_t ws_size,
                              hipStream_t stream)
{
    const int*   X  = (const int*)d_in[0];
    const int*   Y  = (const int*)d_in[1];
    const float* lw = (const float*)d_in[2];
    const float* gw = (const float*)d_in[3];
    const float* sw = (const float*)d_in[4];
    const float* pw = (const float*)d_in[5];
    float* out = (float*)d_out;

    const int B = in_sizes[0] / 4;   // 65536
    const int T = in_sizes[1] / B;   // 512

    const size_t seeds_off = 0;
    const size_t bits_off  = (size_t)B * 16 * 4;         // 4.19 MB
    const size_t prm_off   = bits_off + (size_t)B * 16 * 4;
    const size_t ws_need   = prm_off + (size_t)B * 4 * 4; // ~9.4 MB

    if (T == 512 && (B % 256) == 0 && ws_size >= ws_need) {
        float*        seeds = (float*)((char*)d_ws + seeds_off);
        unsigned int* bits  = (unsigned int*)((char*)d_ws + bits_off);
        float*        prm   = (float*)((char*)d_ws + prm_off);
        bkt_seed<<<B / 256, 256, 0, stream>>>(X, Y, lw, gw, sw, pw,
                                              seeds, bits, prm, B, T);
        bkt_emit<<<B / 16, 256, 0, stream>>>(seeds, bits, prm, out, B, T);
    } else {
        bkt_fwd<<<B / 256, 256, 0, stream>>>(X, Y, lw, gw, sw, pw, out, B, T);
    }
}